// Round 8
// baseline (195.107 us; speedup 1.0000x reference)
//
#include <hip/hip_runtime.h>
#include <math.h>

#define BB 512
#define SS 50
#define EE 128
#define HH 8
#define RR 32
#define NC 5
#define NSEQ 20000
#define NBS (BB*SS)   // 25600
#define LDK 136       // padded bf16 row stride (ushorts) for LDS A-tile
#define NRB 2048      // region blocks per half (grid-stride)

typedef __attribute__((ext_vector_type(8))) __bf16 bf16x8;
typedef __attribute__((ext_vector_type(4))) float f32x4;
typedef __attribute__((ext_vector_type(4))) unsigned short us4;

__device__ __forceinline__ unsigned short f2bf(float f) {
    unsigned int u = __float_as_uint(f);
    unsigned int r = (u + 0x7fffu + ((u >> 16) & 1u)) >> 16;
    return (unsigned short)r;
}
__device__ __forceinline__ float dot4v(const f32x4& a, const float4& b) {
    return a[0]*b.x + a[1]*b.y + a[2]*b.z + a[3]*b.w;
}

// -------------------- prep: weight transpose/convert + seq histogram --------------------
__global__ __launch_bounds__(256) void prep_kernel(const float* __restrict__ wv,
                                                   const float* __restrict__ wo,
                                                   unsigned short* __restrict__ wvT,
                                                   unsigned short* __restrict__ woT,
                                                   const int* __restrict__ seq,
                                                   int* __restrict__ hist) {
    const int bid = blockIdx.x, t = threadIdx.x;
    if (bid < 128) {
        const int n = bid;
        if (t < 128) wvT[n*EE + t] = f2bf(wv[t*EE + n]);
        else         woT[n*EE + (t - 128)] = f2bf(wo[(t - 128)*EE + n]);
    } else {
        const int i = (bid - 128) * 256 + t;
        if (i < NBS) atomicAdd(&hist[seq[i]], 1);
    }
}

// single block, 1024 threads: exclusive scan of hist (working offsets for scatter)
// + compaction of nonempty j's: jlist[c]=j, jstart[c]=start offset, sentinel jstart[M]=NBS
__global__ __launch_bounds__(1024) void scan_kernel(int* __restrict__ hist,
                                                    int* __restrict__ jlist,
                                                    int* __restrict__ jstart,
                                                    int* __restrict__ Mcount) {
    const int t = threadIdx.x;
    const int CH = 20;                      // 1024*20 >= NSEQ
    const int base = t * CH;
    int val[CH];
    int s = 0, cz = 0;
    #pragma unroll
    for (int i = 0; i < CH; ++i) {
        int idx = base + i;
        int v = (idx < NSEQ) ? hist[idx] : 0;
        val[i] = v;
        s += v;
        cz += (v > 0) ? 1 : 0;
    }
    const int lane = t & 63, w = t >> 6;    // 16 waves
    int incl = s, incl2 = cz;
    #pragma unroll
    for (int off = 1; off < 64; off <<= 1) {
        int n1 = __shfl_up(incl, off);
        int n2 = __shfl_up(incl2, off);
        if (lane >= off) { incl += n1; incl2 += n2; }
    }
    __shared__ int wsum[16], wsum2[16];
    if (lane == 63) { wsum[w] = incl; wsum2[w] = incl2; }
    __syncthreads();
    if (t == 0) {
        int a = 0, b = 0;
        #pragma unroll
        for (int k = 0; k < 16; ++k) {
            int v1 = wsum[k], v2 = wsum2[k];
            wsum[k] = a; wsum2[k] = b;
            a += v1; b += v2;
        }
    }
    __syncthreads();
    int e  = incl  - s  + wsum[w];
    int c2 = incl2 - cz + wsum2[w];
    #pragma unroll
    for (int i = 0; i < CH; ++i) {
        int idx = base + i;
        if (idx < NSEQ) {
            hist[idx] = e;
            if (val[i] > 0) { jlist[c2] = idx; jstart[c2] = e; ++c2; }
            e += val[i];
        }
    }
    if (t == 1023) {
        int M = wsum2[15] + incl2;          // total nonempty j count
        Mcount[0] = M;
        jstart[M] = NBS;                    // sentinel: end of last nonempty j
    }
}

// scatter: group occurrences by j; precompute bs|mask and item-row per position
__global__ __launch_bounds__(256) void scatter_kernel(const int* __restrict__ seq,
                                                      const int* __restrict__ neighbor,
                                                      const int* __restrict__ item,
                                                      int* __restrict__ hist,
                                                      int* __restrict__ pinfo,
                                                      int* __restrict__ pitem) {
    int i = blockIdx.x * 256 + threadIdx.x;
    if (i < NBS) {
        int pos = atomicAdd(&hist[seq[i]], 1);
        pinfo[pos] = i | ((neighbor[i] > 0) ? 0 : 0x80000000);
        pitem[pos] = item[(unsigned)i / SS];
    }
}

// -------------------- Kernel 1: attention, all-MFMA (unchanged, verified) --------------------
__global__ __launch_bounds__(256, 4) void attn_kernel(
    const int* __restrict__ user,
    const int* __restrict__ neighbor,
    const float* __restrict__ uet,
    const float* __restrict__ wq, const float* __restrict__ bq,
    const float* __restrict__ wk, const float* __restrict__ bk,
    const float* __restrict__ bv, const float* __restrict__ bo,
    const unsigned short* __restrict__ wvT, const unsigned short* __restrict__ woT,
    float* __restrict__ ws_ne2)
{
    __shared__ unsigned short kA[64*LDK];
    __shared__ unsigned short qkvT[16][EE];
    __shared__ float ue[EE];
    __shared__ float qs[EE];
    __shared__ float qkb[HH];
    __shared__ float attn_s[HH][64];
    __shared__ float maskadd[64];

    const int b = blockIdx.x;
    const int t = threadIdx.x;

    if (t < EE) ue[t] = uet[(size_t)user[b]*EE + t];
    if (t < 64) maskadd[t] = (t < SS && neighbor[b*SS + t] > 0) ? 0.f : -1e9f;
    for (int idx = t; idx < SS*32; idx += 256) {
        int s = idx >> 5, g = idx & 31;
        float4 v = ((const float4*)(uet + (size_t)neighbor[b*SS + s]*EE))[g];
        us4 o; o.x = f2bf(v.x); o.y = f2bf(v.y); o.z = f2bf(v.z); o.w = f2bf(v.w);
        *(us4*)&kA[s*LDK + g*4] = o;
    }
    for (int idx = t; idx < 14*LDK; idx += 256) kA[50*LDK + idx] = 0;
    for (int idx = t; idx < 8*EE; idx += 256) qkvT[8 + (idx >> 7)][idx & 127] = 0;
    __syncthreads();

    if (t < EE) {
        float acc = bq[t];
        #pragma unroll 4
        for (int e = 0; e < EE; ++e) acc = fmaf(ue[e], wq[e*EE + t], acc);
        qs[t] = acc;
    }
    __syncthreads();

    {
        const int e = t >> 1, h0 = (t & 1) * 4;
        const float* wrow = wk + e*EE;
        #pragma unroll
        for (int j = 0; j < 4; ++j) {
            int h = h0 + j;
            float acc = 0.f;
            #pragma unroll
            for (int d = 0; d < 16; ++d) acc = fmaf(qs[h*16 + d], wrow[h*16 + d], acc);
            qkvT[h][e] = f2bf(acc);
        }
    }
    if (t < HH) {
        float acc = 0.f;
        #pragma unroll
        for (int d = 0; d < 16; ++d) acc = fmaf(qs[t*16 + d], bk[t*16 + d], acc);
        qkb[t] = acc;
    }
    __syncthreads();

    const int w    = t >> 6;
    const int l    = t & 63;
    const int lrow = l & 15;
    const int kg   = l >> 4;

    bf16x8 a0 = *(const bf16x8*)&kA[(w*16 + lrow)*LDK +  0 + kg*8];
    bf16x8 a1 = *(const bf16x8*)&kA[(w*16 + lrow)*LDK + 32 + kg*8];
    bf16x8 a2 = *(const bf16x8*)&kA[(w*16 + lrow)*LDK + 64 + kg*8];
    bf16x8 a3 = *(const bf16x8*)&kA[(w*16 + lrow)*LDK + 96 + kg*8];

    {
        bf16x8 b0 = *(const bf16x8*)&qkvT[lrow][ 0 + kg*8];
        bf16x8 b1 = *(const bf16x8*)&qkvT[lrow][32 + kg*8];
        bf16x8 b2 = *(const bf16x8*)&qkvT[lrow][64 + kg*8];
        bf16x8 b3 = *(const bf16x8*)&qkvT[lrow][96 + kg*8];
        f32x4 c = {0.f, 0.f, 0.f, 0.f};
        c = __builtin_amdgcn_mfma_f32_16x16x32_bf16(a0, b0, c, 0, 0, 0);
        c = __builtin_amdgcn_mfma_f32_16x16x32_bf16(a1, b1, c, 0, 0, 0);
        c = __builtin_amdgcn_mfma_f32_16x16x32_bf16(a2, b2, c, 0, 0, 0);
        c = __builtin_amdgcn_mfma_f32_16x16x32_bf16(a3, b3, c, 0, 0, 0);
        const int h = lrow;
        if (h < HH) {
            #pragma unroll
            for (int rg = 0; rg < 4; ++rg) {
                const int row = w*16 + kg*4 + rg;
                attn_s[h][row] = (c[rg] + qkb[h]) * 0.25f + maskadd[row];
            }
        }
    }
    __syncthreads();

    if (t < 64) {
        int h = t >> 3, ll = t & 7;
        float mx = -3e38f;
        #pragma unroll
        for (int i = 0; i < 7; ++i) { int s = i*8 + ll; if (s < SS) mx = fmaxf(mx, attn_s[h][s]); }
        mx = fmaxf(mx, __shfl_xor(mx, 1));
        mx = fmaxf(mx, __shfl_xor(mx, 2));
        mx = fmaxf(mx, __shfl_xor(mx, 4));
        float ev[7]; float sm_ = 0.f;
        #pragma unroll
        for (int i = 0; i < 7; ++i) {
            int s = i*8 + ll; ev[i] = 0.f;
            if (s < SS) { ev[i] = expf(attn_s[h][s] - mx); sm_ += ev[i]; }
        }
        sm_ += __shfl_xor(sm_, 1);
        sm_ += __shfl_xor(sm_, 2);
        sm_ += __shfl_xor(sm_, 4);
        float inv = 1.f / sm_;
        #pragma unroll
        for (int i = 0; i < 7; ++i) { int s = i*8 + ll; if (s < SS) attn_s[h][s] = ev[i] * inv; }
    }
    __syncthreads();

    f32x4 acc[8];
    #pragma unroll
    for (int nt = 0; nt < 8; ++nt) {
        const unsigned short* bp = wvT + (nt*16 + lrow)*EE + kg*8;
        bf16x8 b0 = *(const bf16x8*)&bp[0];
        bf16x8 b1 = *(const bf16x8*)&bp[32];
        bf16x8 b2 = *(const bf16x8*)&bp[64];
        bf16x8 b3 = *(const bf16x8*)&bp[96];
        f32x4 c = {0.f, 0.f, 0.f, 0.f};
        c = __builtin_amdgcn_mfma_f32_16x16x32_bf16(a0, b0, c, 0, 0, 0);
        c = __builtin_amdgcn_mfma_f32_16x16x32_bf16(a1, b1, c, 0, 0, 0);
        c = __builtin_amdgcn_mfma_f32_16x16x32_bf16(a2, b2, c, 0, 0, 0);
        c = __builtin_amdgcn_mfma_f32_16x16x32_bf16(a3, b3, c, 0, 0, 0);
        acc[nt] = c;
    }
    #pragma unroll
    for (int nt = 0; nt < 8; ++nt) {
        const int col = nt*16 + lrow;
        const float bvc = bv[col];
        #pragma unroll
        for (int rg = 0; rg < 4; ++rg) {
            const int row = w*16 + kg*4 + rg;
            const float av = (row < SS) ? attn_s[nt][row] : 0.f;
            kA[row*LDK + col] = f2bf((acc[nt][rg] + bvc) * av);
        }
    }
    __syncthreads();

    bf16x8 c0 = *(const bf16x8*)&kA[(w*16 + lrow)*LDK +  0 + kg*8];
    bf16x8 c1 = *(const bf16x8*)&kA[(w*16 + lrow)*LDK + 32 + kg*8];
    bf16x8 c2 = *(const bf16x8*)&kA[(w*16 + lrow)*LDK + 64 + kg*8];
    bf16x8 c3 = *(const bf16x8*)&kA[(w*16 + lrow)*LDK + 96 + kg*8];

    #pragma unroll
    for (int nt = 0; nt < 8; ++nt) {
        const unsigned short* bp = woT + (nt*16 + lrow)*EE + kg*8;
        bf16x8 b0 = *(const bf16x8*)&bp[0];
        bf16x8 b1 = *(const bf16x8*)&bp[32];
        bf16x8 b2 = *(const bf16x8*)&bp[64];
        bf16x8 b3 = *(const bf16x8*)&bp[96];
        f32x4 c = {0.f, 0.f, 0.f, 0.f};
        c = __builtin_amdgcn_mfma_f32_16x16x32_bf16(c0, b0, c, 0, 0, 0);
        c = __builtin_amdgcn_mfma_f32_16x16x32_bf16(c1, b1, c, 0, 0, 0);
        c = __builtin_amdgcn_mfma_f32_16x16x32_bf16(c2, b2, c, 0, 0, 0);
        c = __builtin_amdgcn_mfma_f32_16x16x32_bf16(c3, b3, c, 0, 0, 0);
        const int col = nt*16 + lrow;
        const float boc = bo[col];
        #pragma unroll
        for (int rg = 0; rg < 4; ++rg) {
            const int row = w*16 + kg*4 + rg;
            if (row < SS)
                ws_ne2[((size_t)b*SS + row)*EE + col] = c[rg] + boc;
        }
    }
}

// -------------------- Kernel 2: region — grid-stride over nonempty j, dbuf panel prefetch ----
// blocks [0,NRB): np half (iu_lcu . ne2, mask folded); [NRB,2*NRB): ip half (ui_lcu . item_emb)
__global__ __launch_bounds__(256) void region_kernel(
    const float* __restrict__ iu_lcu, const float* __restrict__ ui_lcu,
    const float* __restrict__ ws_ne2, const float* __restrict__ iet,
    const int* __restrict__ jlist, const int* __restrict__ jstart,
    const int* __restrict__ pinfo, const int* __restrict__ pitem,
    const int* __restrict__ Mcount,
    float* __restrict__ ws_np, float* __restrict__ ws_ip)
{
    const int M = Mcount[0];
    const int half = blockIdx.x >> 11;       // NRB = 2048
    int c = blockIdx.x & (NRB - 1);
    if (c >= M) return;

    const int t = threadIdx.x, r = t >> 3, l = t & 7;
    const float* lcu  = half ? ui_lcu : iu_lcu;
    const float* vecs = half ? iet    : ws_ne2;
    float* outb       = half ? ws_ip  : ws_np;

    f32x4 A0, A1, A2, A3, B0, B1, B2, B3;
    int sCur, eCur;
    {
        int j = jlist[c];
        sCur = jstart[c]; eCur = jstart[c+1];
        const f32x4* kp = (const f32x4*)(lcu + ((size_t)j*RR + r)*EE);
        A0 = kp[l]; A1 = kp[l+8]; A2 = kp[l+16]; A3 = kp[l+24];
    }

#define DOTSTORE(P0,P1,P2,P3, v0,v1,v2,v3, info_) {                               \
    float acc_ = dot4v(P0,v0) + dot4v(P1,v1) + dot4v(P2,v2) + dot4v(P3,v3);       \
    acc_ += __shfl_xor(acc_,1); acc_ += __shfl_xor(acc_,2); acc_ += __shfl_xor(acc_,4); \
    if (l == 0) {                                                                 \
        int bs_ = (info_) & 0xFFFF;                                               \
        outb[(size_t)bs_*RR + r] = half ? acc_ : (((info_) < 0) ? 0.f : acc_);    \
    } }

#define STAGE(C0,C1,C2,C3, N0,N1,N2,N3) {                                         \
    const int sC = sCur, eC = eCur, nC = eC - sC;                                 \
    const int cn = c + NRB;                                                       \
    const bool more = (cn < M);                                                   \
    const int jN = more ? jlist[cn] : 0;                                          \
    sCur = more ? jstart[cn]   : 0;                                               \
    eCur = more ? jstart[cn+1] : 0;                                               \
    const int i0 = pinfo[sC];                                                     \
    const int i1 = (nC >= 2) ? pinfo[sC+1] : i0;                                  \
    const int t0 = half ? pitem[sC] : (i0 & 0xFFFF);                              \
    const int t1 = half ? ((nC >= 2) ? pitem[sC+1] : t0) : (i1 & 0xFFFF);         \
    const float4* rb0 = (const float4*)(vecs + (size_t)t0*EE);                    \
    float4 r0 = rb0[l], r1 = rb0[l+8], r2 = rb0[l+16], r3 = rb0[l+24];            \
    float4 s0, s1, s2, s3;                                                        \
    if (nC >= 2) {                                                                \
        const float4* rb1 = (const float4*)(vecs + (size_t)t1*EE);                \
        s0 = rb1[l]; s1 = rb1[l+8]; s2 = rb1[l+16]; s3 = rb1[l+24];               \
    }                                                                             \
    if (more) {                                                                   \
        const f32x4* kp = (const f32x4*)(lcu + ((size_t)jN*RR + r)*EE);           \
        N0 = kp[l]; N1 = kp[l+8]; N2 = kp[l+16]; N3 = kp[l+24];                   \
    }                                                                             \
    DOTSTORE(C0,C1,C2,C3, r0,r1,r2,r3, i0);                                       \
    if (nC >= 2) DOTSTORE(C0,C1,C2,C3, s0,s1,s2,s3, i1);                          \
    for (int o = sC + 2; o < eC; ++o) {                                           \
        const int ii = pinfo[o];                                                  \
        const int tt = half ? pitem[o] : (ii & 0xFFFF);                           \
        const float4* rb = (const float4*)(vecs + (size_t)tt*EE);                 \
        float4 q0 = rb[l], q1 = rb[l+8], q2 = rb[l+16], q3 = rb[l+24];            \
        DOTSTORE(C0,C1,C2,C3, q0,q1,q2,q3, ii);                                   \
    }                                                                             \
    if (!more) break;                                                             \
    c = cn; }

    while (true) {
        STAGE(A0,A1,A2,A3, B0,B1,B2,B3)
        STAGE(B0,B1,B2,B3, A0,A1,A2,A3)
    }
#undef STAGE
#undef DOTSTORE
}

// -------------------- Kernel 3: max over s of np*ip, FC, softmax --------------------
__global__ __launch_bounds__(256) void head_kernel(
    const float* __restrict__ ws_np, const float* __restrict__ ws_ip,
    const float* __restrict__ fc_w, const float* __restrict__ fc_b,
    float* __restrict__ out)
{
    __shared__ float part[8][RR];
    __shared__ float urv[RR];
    __shared__ float lg[NC];
    const int b = blockIdx.x, t = threadIdx.x;
    const int r = t & 31, sub = t >> 5;

    float m = -3e38f;
    for (int s = sub; s < SS; s += 8) {
        const size_t idx = ((size_t)b*SS + s)*RR + r;
        m = fmaxf(m, ws_np[idx] * ws_ip[idx]);
    }
    part[sub][r] = m;
    __syncthreads();
    if (t < RR) {
        float mm = part[0][t];
        #pragma unroll
        for (int k = 1; k < 8; ++k) mm = fmaxf(mm, part[k][t]);
        urv[t] = mm;
    }
    __syncthreads();
    if (t < NC) {
        float acc = fc_b[t];
        #pragma unroll
        for (int rr = 0; rr < RR; ++rr) acc = fmaf(urv[rr], fc_w[rr*NC + t], acc);
        lg[t] = acc;
    }
    __syncthreads();
    if (t < NC) {
        float mx = lg[0];
        #pragma unroll
        for (int cc = 1; cc < NC; ++cc) mx = fmaxf(mx, lg[cc]);
        float sm = 0.f;
        #pragma unroll
        for (int cc = 0; cc < NC; ++cc) sm += expf(lg[cc] - mx);
        out[b*NC + t] = expf(lg[t] - mx) / sm;
    }
}

extern "C" void kernel_launch(void* const* d_in, const int* in_sizes, int n_in,
                              void* d_out, int out_size, void* d_ws, size_t ws_size,
                              hipStream_t stream) {
    const int*   user     = (const int*)d_in[0];
    const int*   item     = (const int*)d_in[1];
    const int*   neighbor = (const int*)d_in[2];
    const int*   seq      = (const int*)d_in[3];
    const float* uet      = (const float*)d_in[4];
    const float* iet      = (const float*)d_in[5];
    const float* ui_lcu   = (const float*)d_in[6];
    const float* iu_lcu   = (const float*)d_in[7];
    const float* wq = (const float*)d_in[8];   const float* bq = (const float*)d_in[9];
    const float* wk = (const float*)d_in[10];  const float* bk = (const float*)d_in[11];
    const float* wv = (const float*)d_in[12];  const float* bv = (const float*)d_in[13];
    const float* wo = (const float*)d_in[14];  const float* bo = (const float*)d_in[15];
    const float* fcw = (const float*)d_in[16]; const float* fcb = (const float*)d_in[17];

    float* ws = (float*)d_ws;
    float* ws_ne2 = ws;                                          // B*S*E f32
    float* ws_np  = ws_ne2 + (size_t)BB*SS*EE;                   // B*S*R f32
    float* ws_ip  = ws_np  + (size_t)BB*SS*RR;                   // B*S*R f32
    unsigned short* wvT = (unsigned short*)(ws_ip + (size_t)BB*SS*RR);  // 128*128 bf16
    unsigned short* woT = wvT + EE*EE;                           // 128*128 bf16
    int* hist   = (int*)(woT + EE*EE);                           // NSEQ (working offsets)
    int* jlist  = hist + NSEQ;                                   // NSEQ (compacted nonempty j)
    int* jstart = jlist + NSEQ;                                  // NSEQ+1 (+ sentinel)
    int* Mcount = jstart + NSEQ + 1;                             // 1
    int* pinfo  = Mcount + 1;                                    // NBS (bs | mask<<31)
    int* pitem  = pinfo + NBS;                                   // NBS (item row)
    float* out = (float*)d_out;

    // ---- prep: conv + hist (fused), scan+compact, scatter ----
    hipMemsetAsync(hist, 0, NSEQ * sizeof(int), stream);
    hipLaunchKernelGGL(prep_kernel, dim3(128 + (NBS + 255)/256), dim3(256), 0, stream,
                       wv, wo, wvT, woT, seq, hist);
    hipLaunchKernelGGL(scan_kernel, dim3(1), dim3(1024), 0, stream,
                       hist, jlist, jstart, Mcount);
    hipLaunchKernelGGL(scatter_kernel, dim3((NBS + 255)/256), dim3(256), 0, stream,
                       seq, neighbor, item, hist, pinfo, pitem);

    // ---- attention (all-MFMA) ----
    hipLaunchKernelGGL(attn_kernel, dim3(BB), dim3(256), 0, stream,
                       user, neighbor, uet,
                       wq, bq, wk, bk, bv, bo, wvT, woT, ws_ne2);

    // ---- region: grid-stride streaming over nonempty j's, both halves ----
    hipLaunchKernelGGL(region_kernel, dim3(2*NRB), dim3(256), 0, stream,
                       iu_lcu, ui_lcu, ws_ne2, iet,
                       jlist, jstart, pinfo, pitem, Mcount, ws_np, ws_ip);

    hipLaunchKernelGGL(head_kernel, dim3(BB), dim3(256), 0, stream,
                       ws_np, ws_ip, fcw, fcb, out);
}